// Round 19
// baseline (131.296 us; speedup 1.0000x reference)
//
#include <hip/hip_runtime.h>
#include <hip/hip_bf16.h>
#include <stdint.h>

// Problem constants (fixed by the reference).
constexpr int T  = 4096;   // contraction dim (K = t)
constexpr int Bb = 8;      // batch
constexpr int C  = 512;    // channels (N)
constexpr int S  = 2048;   // groups (M)
constexpr int BC = Bb * C; // 4096 floats

constexpr int BK = 64;        // K-tile per iteration
constexpr int NK = T / BK;    // 64 iterations

typedef __bf16 bf16x8 __attribute__((ext_vector_type(8)));
typedef float  f32x16 __attribute__((ext_vector_type(16)));
typedef float  f32x4  __attribute__((ext_vector_type(4)));
typedef unsigned int u32;

__device__ inline unsigned pk2(float lo, float hi) {
    union { __hip_bfloat16 h; unsigned short u; } a, b;
    a.h = __float2bfloat16(lo);
    b.h = __float2bfloat16(hi);
    return ((unsigned)b.u << 16) | (unsigned)a.u;
}

__device__ inline int slot16(int s) { return s ^ ((s >> 2) & 7); }

// global -> LDS direct DMA, 16B per lane (r15-verified).
__device__ inline void glds16(const void* g, void* l) {
    __builtin_amdgcn_global_load_lds(
        (const u32 __attribute__((address_space(1)))*)(uintptr_t)g,
        (u32 __attribute__((address_space(3)))*)(u32)(uintptr_t)l,
        16, 0, 0);
}

// Pre-pass (r15/r17-verified): x as bf16 in the B-LDS tile image:
// xTile[b][nt][k][byte], byte = oct*2048 + cc*16 + j*2 holding
// x[t=k*64+oct*8+j][b][c=nt*128+cc]. Blocks 0..15 also write out[0,b,c].
__global__ __launch_bounds__(256) void transpose_x(
    const float* __restrict__ x, __bf16* __restrict__ xT,
    const float* __restrict__ left, float* __restrict__ out)
{
    __shared__ float lds[64][68];
    const int bid = blockIdx.x;        // 8 b x 64 k x 8 c-tiles
    const int tid = threadIdx.x;

    if (bid < 16) {                    // fused left_fill: 16*256 = BC
        const int i = bid * 256 + tid;
        out[i] = left[i & (C - 1)];
    }

    const int b   = bid >> 9;
    const int rem = bid & 511;
    const int t0  = (rem >> 3) * 64;
    const int c0  = (rem & 7) * 64;

#pragma unroll
    for (int it = 0; it < 4; ++it) {
        const int slot = tid + it * 256;
        const int row = slot >> 4, cg = slot & 15;
        f32x4 v = *(const f32x4*)(x + (size_t)(t0 + row) * BC + b * C + c0 + cg * 4);
        *(f32x4*)(&lds[row][cg * 4]) = v;
    }
    __syncthreads();
    const int k = t0 >> 6;
#pragma unroll
    for (int it = 0; it < 2; ++it) {
        const int slot = tid + it * 256;
        const int tg8 = slot >> 6, cr = slot & 63;
        const int c  = c0 + cr;
        const int nt = c >> 7, cc = c & 127;
        uint4 w;
        w.x = pk2(lds[tg8 * 8 + 0][cr], lds[tg8 * 8 + 1][cr]);
        w.y = pk2(lds[tg8 * 8 + 2][cr], lds[tg8 * 8 + 3][cr]);
        w.z = pk2(lds[tg8 * 8 + 4][cr], lds[tg8 * 8 + 5][cr]);
        w.w = pk2(lds[tg8 * 8 + 6][cr], lds[tg8 * 8 + 7][cr]);
        *(uint4*)(xT + ((size_t)(b * 4 + nt) * 64 + k) * 8192 + tg8 * 1024 + cc * 8) = w;
    }
}

// MAIN (round 19) = r18 champion (127.5us: glds-B, spread-A, setprio, raw
// barrier) + DEPTH-2 B DMA over 3 LDS buffers with issue-order flip:
//   LOAD_A(k+1) issued FIRST, then GLDS_B(k+2). The pack's compiler-counted
//   vmcnt wait for the A loads is now vmcnt(2): it drains glds(k+1) (older,
//   needed at COMPUTE(k+1)) but leaves glds(k+2) IN FLIGHT across the
//   barrier and all of iter k+1 (~2 phases of cover vs <1 in r18, where
//   glds(k+1) issued before LOAD_A forced the pack wait to drain it).
// LDS: A 2x16KB @0 | B 3x16KB @32KB = 80KB/block = 160KB/CU (exact fit,
// 2 blocks/CU preserved). Zero extra VGPRs (depth lives in LDS, not regs --
// the r7/r10/r13 spill trap doesn't apply).
// Race audit: glds(k+2)->bufB[(k+2)%3]; last read of that buf is
// COMPUTE(k-1); barrier(k-1) separates. B(k+1) readiness: pack(k) vmcnt
// drains glds(k+1), then barrier(k). A-side identical to r17/r18.
__global__ __launch_bounds__(512, 4) void ds_gemm_glds(
    const __bf16* __restrict__ xT,
    const float* __restrict__ mask,
    float* __restrict__ out)
{
    __shared__ __align__(16) unsigned char smem[81920];  // A: 2x16KB | B: 3x16KB

    const int bid0 = blockIdx.x;
    const int xcd  = bid0 & 7;
    const int slot = bid0 >> 3;
    const int b    = xcd;                 // batch plane owned by this XCD
    const int mt   = slot & 15;           // s-tile
    const int nt   = (slot >> 4) & 3;     // c-tile

    const int tid  = threadIdx.x;
    const int lane = tid & 63;
    const int wave = tid >> 6;       // 0..7
    const int h    = wave >> 2;      // K-group (0..1)
    const int wq   = wave & 3;
    const int wm = wq >> 1;          // s-half
    const int wn = wq & 1;           // c-half
    const int lm = lane & 31;
    const int kg = lane >> 5;

    // ---- A (mask) staging: ALL 512 threads; thread = (col-group, t-quad) ----
    const int sg = tid & 31;         // 4-wide col group
    const int tq = tid >> 5;         // t-quad 0..15 (4 t-rows each)

    const float* gsrc = mask + (size_t)b * T * S + (size_t)(tq * 4) * S + mt * 128 + sg * 4;
    const size_t gstep = (size_t)S * BK;

    int waddr[4];
#pragma unroll
    for (int j = 0; j < 4; ++j)
        waddr[j] = (tq >> 1) * 2048 + slot16(sg * 4 + j) * 16 + (tq & 1) * 8;

    // ---- fragment addresses (oct = h*4 + kk*2 + kg) ----
    int raddrA[2][2], roffB[2][2];
#pragma unroll
    for (int kk = 0; kk < 2; ++kk)
#pragma unroll
        for (int q = 0; q < 2; ++q) {
            const int oct = h * 4 + kk * 2 + kg;
            raddrA[kk][q] = oct * 2048 + slot16(wm * 64 + q * 32 + lm) * 16;
            roffB[kk][q]  = oct * 2048 + (wn * 64 + q * 32 + lm) * 16;  // linear image
        }

    // ---- B global tile base (this block's b,nt panel) ----
    const char* xtile = (const char*)(xT + ((size_t)(b * 4 + nt) * 64) * 8192);

    f32x16 acc[2][2] = {};
    f32x4  L[4];

#define LOAD_A(k)                                                           \
    {                                                                       \
        const float* p_ = gsrc + (size_t)(k) * gstep;                       \
        _Pragma("unroll") for (int r = 0; r < 4; ++r)                       \
            L[r] = *(const f32x4*)(p_ + (size_t)r * S);                     \
    }

#define WRITE_A(buf)                                                        \
    {                                                                       \
        const int boff_ = (buf) * 16384;                                    \
        _Pragma("unroll") for (int j = 0; j < 4; ++j) {                     \
            uint2 w_;                                                       \
            w_.x = pk2(L[0][j], L[1][j]);                                   \
            w_.y = pk2(L[2][j], L[3][j]);                                   \
            *(uint2*)(smem + boff_ + waddr[j]) = w_;                        \
        }                                                                   \
    }

// 16KB B tile via 2 glds/thread into buffer (k)%3 (r15-verified pattern).
#define GLDS_B(k)                                                           \
    {                                                                       \
        const char* gb_ = xtile + (size_t)(k) * 16384;                      \
        char* lb_ = (char*)smem + 32768 + ((k) % 3) * 16384 + wave * 1024;  \
        glds16(gb_ + tid * 16,        lb_);                                 \
        glds16(gb_ + tid * 16 + 8192, lb_ + 8192);                         \
    }

#define COMPUTE(k)                                                          \
    {                                                                       \
        const int ba_ = ((k) & 1) * 16384;                                  \
        const int bb_ = 32768 + ((k) % 3) * 16384;                          \
        __builtin_amdgcn_s_setprio(1);                                      \
        _Pragma("unroll") for (int kk = 0; kk < 2; ++kk) {                  \
            bf16x8 a0_ = *(const bf16x8*)(smem + ba_ + raddrA[kk][0]);      \
            bf16x8 a1_ = *(const bf16x8*)(smem + ba_ + raddrA[kk][1]);      \
            bf16x8 b0_ = *(const bf16x8*)(smem + bb_ + roffB[kk][0]);       \
            bf16x8 b1_ = *(const bf16x8*)(smem + bb_ + roffB[kk][1]);       \
            acc[0][0] = __builtin_amdgcn_mfma_f32_32x32x16_bf16(a0_, b0_, acc[0][0], 0, 0, 0); \
            acc[0][1] = __builtin_amdgcn_mfma_f32_32x32x16_bf16(a0_, b1_, acc[0][1], 0, 0, 0); \
            acc[1][0] = __builtin_amdgcn_mfma_f32_32x32x16_bf16(a1_, b0_, acc[1][0], 0, 0, 0); \
            acc[1][1] = __builtin_amdgcn_mfma_f32_32x32x16_bf16(a1_, b1_, acc[1][1], 0, 0, 0); \
        }                                                                   \
        __builtin_amdgcn_s_setprio(0);                                      \
    }

    // Prologue: B tiles 0 and 1 in flight, A tile 0 staged; full drain once.
    GLDS_B(0);
    GLDS_B(1);
    LOAD_A(0);
    WRITE_A(0);            // drains everything older (both glds batches OK here)
    __syncthreads();

    for (int k = 0; k < NK; ++k) {
        if (k + 1 < NK) LOAD_A(k + 1);     // A loads FIRST (older in vmcnt queue)
        if (k + 2 < NK) GLDS_B(k + 2);     // newest: survives the pack's A-wait
        COMPUTE(k);
        if (k + 1 < NK) WRITE_A((k + 1) & 1);  // vmcnt(2): drains A + glds(k+1)
        asm volatile("s_waitcnt lgkmcnt(0)" ::: "memory");   // ds_writes visible
        __builtin_amdgcn_s_barrier();                         // raw: no vmcnt drain
        __builtin_amdgcn_sched_barrier(0);
    }

#undef LOAD_A
#undef WRITE_A
#undef GLDS_B
#undef COMPUTE

    // -------- cross-K-group reduction via LDS, then store (h=0 only) --------
    __syncthreads();
    if (h == 1) {
#pragma unroll
        for (int m2 = 0; m2 < 2; ++m2)
#pragma unroll
            for (int n2 = 0; n2 < 2; ++n2) {
                unsigned char* base = smem + (wave - 4) * 16384 + (m2 * 2 + n2) * 4096 + lane * 16;
#pragma unroll
                for (int r4 = 0; r4 < 4; ++r4) {
                    f32x4 v = { acc[m2][n2][r4 * 4 + 0], acc[m2][n2][r4 * 4 + 1],
                                acc[m2][n2][r4 * 4 + 2], acc[m2][n2][r4 * 4 + 3] };
                    *(f32x4*)(base + r4 * 1024) = v;
                }
            }
    }
    __syncthreads();
    if (h == 0) {
#pragma unroll
        for (int m2 = 0; m2 < 2; ++m2)
#pragma unroll
            for (int n2 = 0; n2 < 2; ++n2) {
                const unsigned char* base = smem + wave * 16384 + (m2 * 2 + n2) * 4096 + lane * 16;
#pragma unroll
                for (int r4 = 0; r4 < 4; ++r4) {
                    f32x4 v = *(const f32x4*)(base + r4 * 1024);
#pragma unroll
                    for (int j = 0; j < 4; ++j) acc[m2][n2][r4 * 4 + j] += v[j];
                }
            }
        const int s_w = mt * 128 + wm * 64;
        const int c_w = nt * 128 + wn * 64;
        float* outp = out + BC;
#pragma unroll
        for (int m2 = 0; m2 < 2; ++m2)
#pragma unroll
            for (int n2 = 0; n2 < 2; ++n2)
#pragma unroll
                for (int r = 0; r < 16; ++r) {
                    const int row = (r & 3) + 8 * (r >> 2) + 4 * kg;
                    outp[(size_t)(s_w + m2 * 32 + row) * BC + b * C + c_w + n2 * 32 + lm]
                        = acc[m2][n2][r];
                }
    }
}

// out[0,b,c] = leftmost[c]  (standalone, used only by the fallback path)
__global__ void left_fill(const float* __restrict__ left, float* __restrict__ out) {
    int i = blockIdx.x * blockDim.x + threadIdx.x;
    if (i < BC) out[i] = left[i & (C - 1)];
}

// ---------- FALLBACK (ws too small): round-8 champion kernel verbatim ----------
__global__ __launch_bounds__(512, 4) void ds_gemm_fb(
    const float* __restrict__ x, const float* __restrict__ mask, float* __restrict__ out)
{
    __shared__ __align__(16) unsigned char smem[65536];
    const int bid0 = blockIdx.x;
    const int xcd = bid0 & 7, slot = bid0 >> 3;
    const int b = xcd, mt = slot & 15, nt = (slot >> 4) & 3;
    const int tid = threadIdx.x, lane = tid & 63, wave = tid >> 6;
    const int h = wave >> 2, wq = wave & 3, wm = wq >> 1, wn = wq & 1;
    const int lm = lane & 31, kg = lane >> 5;
    const int ii = tid & 255, sg = ii & 31, tg = ii >> 5;
    const bool stB = (tid >= 256);
    const float* gsrc = stB
        ? x    + (size_t)(tg * 8) * BC + b * C + nt * 128 + sg * 4
        : mask + (size_t)b * T * S + (size_t)(tg * 8) * S + mt * 128 + sg * 4;
    const size_t grow = stB ? (size_t)BC : (size_t)S;
    const size_t gstep = grow * BK;
    int waddr[4];
#pragma unroll
    for (int j = 0; j < 4; ++j)
        waddr[j] = (stB ? 16384 : 0) + tg * 2048 + slot16(sg * 4 + j) * 16;
    int raddrA[2][2], raddrB[2][2];
#pragma unroll
    for (int kk = 0; kk < 2; ++kk)
#pragma unroll
        for (int q = 0; q < 2; ++q) {
            const int oct = h * 4 + kk * 2 + kg;
            raddrA[kk][q] = oct * 2048 + slot16(wm * 64 + q * 32 + lm) * 16;
            raddrB[kk][q] = 16384 + oct * 2048 + slot16(wn * 64 + q * 32 + lm) * 16;
        }
    f32x16 acc[2][2] = {};
    f32x4 L[8];
#define LOAD_TILE(k) { const float* p_ = gsrc + (size_t)(k) * gstep; \
    _Pragma("unroll") for (int r = 0; r < 8; ++r) L[r] = *(const f32x4*)(p_ + (size_t)r * grow); }
#define WRITE_TILE(buf) { const int boff_ = (buf) * 32768; \
    _Pragma("unroll") for (int j = 0; j < 4; ++j) { uint4 w_; \
        w_.x = pk2(L[0][j], L[1][j]); w_.y = pk2(L[2][j], L[3][j]); \
        w_.z = pk2(L[4][j], L[5][j]); w_.w = pk2(L[6][j], L[7][j]); \
        *(uint4*)(smem + boff_ + waddr[j]) = w_; } }
#define COMPUTE(buf) { const int boff_ = (buf) * 32768; \
    _Pragma("unroll") for (int kk = 0; kk < 2; ++kk) { \
        bf16x8 a0_ = *(const bf16x8*)(smem + boff_ + raddrA[kk][0]); \
        bf16x8 a1_ = *(const bf16x8*)(smem + boff_ + raddrA[kk][1]); \
        bf16x8 b0_ = *(const bf16x8*)(smem + boff_ + raddrB[kk][0]); \
        bf16x8 b1_ = *(const bf16x8*)(smem + boff_ + raddrB[kk][1]); \
        acc[0][0] = __builtin_amdgcn_mfma_f32_32x32x16_bf16(a0_, b0_, acc[0][0], 0, 0, 0); \
        acc[0][1] = __builtin_amdgcn_mfma_f32_32x32x16_bf16(a0_, b1_, acc[0][1], 0, 0, 0); \
        acc[1][0] = __builtin_amdgcn_mfma_f32_32x32x16_bf16(a1_, b0_, acc[1][0], 0, 0, 0); \
        acc[1][1] = __builtin_amdgcn_mfma_f32_32x32x16_bf16(a1_, b1_, acc[1][1], 0, 0, 0); } }
    LOAD_TILE(0);
    for (int k = 0; k < NK; ++k) {
        WRITE_TILE(k & 1);
        if (k + 1 < NK) LOAD_TILE(k + 1);
        __syncthreads();
        COMPUTE(k & 1);
    }
#undef LOAD_TILE
#undef WRITE_TILE
#undef COMPUTE
    __syncthreads();
    if (h == 1) {
#pragma unroll
        for (int m2 = 0; m2 < 2; ++m2)
#pragma unroll
            for (int n2 = 0; n2 < 2; ++n2) {
                unsigned char* base = smem + (wave - 4) * 16384 + (m2 * 2 + n2) * 4096 + lane * 16;
#pragma unroll
                for (int r4 = 0; r4 < 4; ++r4) {
                    f32x4 v = { acc[m2][n2][r4 * 4 + 0], acc[m2][n2][r4 * 4 + 1],
                                acc[m2][n2][r4 * 4 + 2], acc[m2][n2][r4 * 4 + 3] };
                    *(f32x4*)(base + r4 * 1024) = v;
                }
            }
    }
    __syncthreads();
    if (h == 0) {
#pragma unroll
        for (int m2 = 0; m2 < 2; ++m2)
#pragma unroll
            for (int n2 = 0; n2 < 2; ++n2) {
                const unsigned char* base = smem + wave * 16384 + (m2 * 2 + n2) * 4096 + lane * 16;
#pragma unroll
                for (int r4 = 0; r4 < 4; ++r4) {
                    f32x4 v = *(const f32x4*)(base + r4 * 1024);
#pragma unroll
                    for (int j = 0; j < 4; ++j) acc[m2][n2][r4 * 4 + j] += v[j];
                }
            }
        const int s_w = mt * 128 + wm * 64;
        const int c_w = nt * 128 + wn * 64;
        float* outp = out + BC;
#pragma unroll
    for (int m2 = 0; m2 < 2; ++m2)
#pragma unroll
        for (int n2 = 0; n2 < 2; ++n2)
#pragma unroll
            for (int r = 0; r < 16; ++r) {
                const int row = (r & 3) + 8 * (r >> 2) + 4 * kg;
                outp[(size_t)(s_w + m2 * 32 + row) * BC + b * C + c_w + n2 * 32 + lm]
                    = acc[m2][n2][r];
            }
    }
}

extern "C" void kernel_launch(void* const* d_in, const int* in_sizes, int n_in,
                              void* d_out, int out_size, void* d_ws, size_t ws_size,
                              hipStream_t stream) {
    const float* x    = (const float*)d_in[0];  // [T,B,C] fp32
    const float* mask = (const float*)d_in[1];  // [B,T,S] fp32
    const float* left = (const float*)d_in[3];  // [1,1,C] fp32
    float* out = (float*)d_out;                 // [S+1,B,C] fp32

    const size_t XT_BYTES = (size_t)T * Bb * C * sizeof(__bf16);  // 32 MiB
    if (ws_size >= XT_BYTES) {
        __bf16* xT = (__bf16*)d_ws;
        transpose_x<<<Bb * (T / 64) * (C / 64), 256, 0, stream>>>(x, xT, left, out);
        ds_gemm_glds<<<Bb * (S / 128) * (C / 128), 512, 0, stream>>>(xT, mask, out);
    } else {
        left_fill<<<BC / 256, 256, 0, stream>>>(left, out);
        ds_gemm_fb<<<Bb * (S / 128) * (C / 128), 512, 0, stream>>>(x, mask, out);
    }
}

// Round 20
// 126.815 us; speedup vs baseline: 1.0353x; 1.0353x over previous
//
#include <hip/hip_runtime.h>
#include <hip/hip_bf16.h>
#include <stdint.h>

// Problem constants (fixed by the reference).
constexpr int T  = 4096;   // contraction dim (K = t)
constexpr int Bb = 8;      // batch
constexpr int C  = 512;    // channels (N)
constexpr int S  = 2048;   // groups (M)
constexpr int BC = Bb * C; // 4096 floats

constexpr int BK = 64;        // K-tile per iteration
constexpr int NK = T / BK;    // 64 iterations

typedef __bf16 bf16x8 __attribute__((ext_vector_type(8)));
typedef float  f32x16 __attribute__((ext_vector_type(16)));
typedef float  f32x4  __attribute__((ext_vector_type(4)));
typedef unsigned int u32;

__device__ inline unsigned pk2(float lo, float hi) {
    union { __hip_bfloat16 h; unsigned short u; } a, b;
    a.h = __float2bfloat16(lo);
    b.h = __float2bfloat16(hi);
    return ((unsigned)b.u << 16) | (unsigned)a.u;
}

__device__ inline int slot16(int s) { return s ^ ((s >> 2) & 7); }

// global -> LDS direct DMA, 16B per lane (r15-verified).
__device__ inline void glds16(const void* g, void* l) {
    __builtin_amdgcn_global_load_lds(
        (const u32 __attribute__((address_space(1)))*)(uintptr_t)g,
        (u32 __attribute__((address_space(3)))*)(u32)(uintptr_t)l,
        16, 0, 0);
}

// Pre-pass (r15/r17-verified): x as bf16 in the B-LDS tile image:
// xTile[b][nt][k][byte], byte = oct*2048 + cc*16 + j*2 holding
// x[t=k*64+oct*8+j][b][c=nt*128+cc]. Blocks 0..15 also write out[0,b,c]
// (fused left_fill).
__global__ __launch_bounds__(256) void transpose_x(
    const float* __restrict__ x, __bf16* __restrict__ xT,
    const float* __restrict__ left, float* __restrict__ out)
{
    __shared__ float lds[64][68];
    const int bid = blockIdx.x;        // 8 b x 64 k x 8 c-tiles
    const int tid = threadIdx.x;

    if (bid < 16) {                    // fused left_fill: 16*256 = BC
        const int i = bid * 256 + tid;
        out[i] = left[i & (C - 1)];
    }

    const int b   = bid >> 9;
    const int rem = bid & 511;
    const int t0  = (rem >> 3) * 64;
    const int c0  = (rem & 7) * 64;

#pragma unroll
    for (int it = 0; it < 4; ++it) {
        const int slot = tid + it * 256;
        const int row = slot >> 4, cg = slot & 15;
        f32x4 v = *(const f32x4*)(x + (size_t)(t0 + row) * BC + b * C + c0 + cg * 4);
        *(f32x4*)(&lds[row][cg * 4]) = v;
    }
    __syncthreads();
    const int k = t0 >> 6;
#pragma unroll
    for (int it = 0; it < 2; ++it) {
        const int slot = tid + it * 256;
        const int tg8 = slot >> 6, cr = slot & 63;
        const int c  = c0 + cr;
        const int nt = c >> 7, cc = c & 127;
        uint4 w;
        w.x = pk2(lds[tg8 * 8 + 0][cr], lds[tg8 * 8 + 1][cr]);
        w.y = pk2(lds[tg8 * 8 + 2][cr], lds[tg8 * 8 + 3][cr]);
        w.z = pk2(lds[tg8 * 8 + 4][cr], lds[tg8 * 8 + 5][cr]);
        w.w = pk2(lds[tg8 * 8 + 6][cr], lds[tg8 * 8 + 7][cr]);
        *(uint4*)(xT + ((size_t)(b * 4 + nt) * 64 + k) * 8192 + tg8 * 1024 + cc * 8) = w;
    }
}

// MAIN (final, = round-18 champion, 127.5us): 128x128 tile, BK=64, 8 waves
// with within-block split-K, 2 blocks/CU, chunked XCD swizzle (b = XCD),
// glds-B DMA from the pre-tiled bf16 image, A (mask) reg-staged across all
// 512 threads, raw-barrier loop (lgkmcnt(0) + s_barrier, no vmcnt drain),
// T5 s_setprio(1/0) around the MFMA cluster.
// Session ladder: 254 -> 161 (16 waves/CU) -> 142 (XCD swizzle) -> 141
// (glds-B + bf16 transpose pre-pass) -> 134 (spread-A + fused fill) ->
// 127.5 (setprio). Falsified: fp32-atomic split-K, depth-2 REGISTER
// staging at 128-VGPR cap (spills), 1 or 4 blocks/CU, mini-8-phase,
// direct-B-from-global (scatter), depth-2 B DMA (neutral-negative).
__global__ __launch_bounds__(512, 4) void ds_gemm_glds(
    const __bf16* __restrict__ xT,
    const float* __restrict__ mask,
    float* __restrict__ out)
{
    __shared__ __align__(16) unsigned char smem[65536];  // A: 2x16KB | B: 2x16KB

    const int bid0 = blockIdx.x;
    const int xcd  = bid0 & 7;
    const int slot = bid0 >> 3;
    const int b    = xcd;                 // batch plane owned by this XCD
    const int mt   = slot & 15;           // s-tile
    const int nt   = (slot >> 4) & 3;     // c-tile

    const int tid  = threadIdx.x;
    const int lane = tid & 63;
    const int wave = tid >> 6;       // 0..7
    const int h    = wave >> 2;      // K-group (0..1)
    const int wq   = wave & 3;
    const int wm = wq >> 1;          // s-half
    const int wn = wq & 1;           // c-half
    const int lm = lane & 31;
    const int kg = lane >> 5;

    // ---- A (mask) staging: ALL 512 threads; thread = (col-group, t-quad) ----
    const int sg = tid & 31;         // 4-wide col group
    const int tq = tid >> 5;         // t-quad 0..15 (4 t-rows each)

    const float* gsrc = mask + (size_t)b * T * S + (size_t)(tq * 4) * S + mt * 128 + sg * 4;
    const size_t gstep = (size_t)S * BK;

    int waddr[4];
#pragma unroll
    for (int j = 0; j < 4; ++j)
        waddr[j] = (tq >> 1) * 2048 + slot16(sg * 4 + j) * 16 + (tq & 1) * 8;

    // ---- fragment addresses (oct = h*4 + kk*2 + kg) ----
    int raddrA[2][2], roffB[2][2];
#pragma unroll
    for (int kk = 0; kk < 2; ++kk)
#pragma unroll
        for (int q = 0; q < 2; ++q) {
            const int oct = h * 4 + kk * 2 + kg;
            raddrA[kk][q] = oct * 2048 + slot16(wm * 64 + q * 32 + lm) * 16;
            roffB[kk][q]  = oct * 2048 + (wn * 64 + q * 32 + lm) * 16;  // linear image
        }

    // ---- B global tile base (this block's b,nt panel) ----
    const char* xtile = (const char*)(xT + ((size_t)(b * 4 + nt) * 64) * 8192);

    f32x16 acc[2][2] = {};
    f32x4  L[4];

#define LOAD_A(k)                                                           \
    {                                                                       \
        const float* p_ = gsrc + (size_t)(k) * gstep;                       \
        _Pragma("unroll") for (int r = 0; r < 4; ++r)                       \
            L[r] = *(const f32x4*)(p_ + (size_t)r * S);                     \
    }

#define WRITE_A(buf)                                                        \
    {                                                                       \
        const int boff_ = (buf) * 16384;                                    \
        _Pragma("unroll") for (int j = 0; j < 4; ++j) {                     \
            uint2 w_;                                                       \
            w_.x = pk2(L[0][j], L[1][j]);                                   \
            w_.y = pk2(L[2][j], L[3][j]);                                   \
            *(uint2*)(smem + boff_ + waddr[j]) = w_;                        \
        }                                                                   \
    }

// 16KB B tile via 2 glds rounds (r15-verified).
#define GLDS_B(k)                                                           \
    {                                                                       \
        const char* gb_ = xtile + (size_t)(k) * 16384;                      \
        char* lb_ = (char*)smem + 32768 + ((k) & 1) * 16384 + wave * 1024;  \
        glds16(gb_ + tid * 16,        lb_);                                 \
        glds16(gb_ + tid * 16 + 8192, lb_ + 8192);                         \
    }

#define COMPUTE(k)                                                          \
    {                                                                       \
        const int ba_ = ((k) & 1) * 16384;                                  \
        const int bb_ = 32768 + ((k) & 1) * 16384;                          \
        __builtin_amdgcn_s_setprio(1);                                      \
        _Pragma("unroll") for (int kk = 0; kk < 2; ++kk) {                  \
            bf16x8 a0_ = *(const bf16x8*)(smem + ba_ + raddrA[kk][0]);      \
            bf16x8 a1_ = *(const bf16x8*)(smem + ba_ + raddrA[kk][1]);      \
            bf16x8 b0_ = *(const bf16x8*)(smem + bb_ + roffB[kk][0]);       \
            bf16x8 b1_ = *(const bf16x8*)(smem + bb_ + roffB[kk][1]);       \
            acc[0][0] = __builtin_amdgcn_mfma_f32_32x32x16_bf16(a0_, b0_, acc[0][0], 0, 0, 0); \
            acc[0][1] = __builtin_amdgcn_mfma_f32_32x32x16_bf16(a0_, b1_, acc[0][1], 0, 0, 0); \
            acc[1][0] = __builtin_amdgcn_mfma_f32_32x32x16_bf16(a1_, b0_, acc[1][0], 0, 0, 0); \
            acc[1][1] = __builtin_amdgcn_mfma_f32_32x32x16_bf16(a1_, b1_, acc[1][1], 0, 0, 0); \
        }                                                                   \
        __builtin_amdgcn_s_setprio(0);                                      \
    }

    // Prologue: stage tile 0 (full drain once is fine).
    GLDS_B(0);
    LOAD_A(0);
    WRITE_A(0);
    __syncthreads();

    for (int k = 0; k < NK; ++k) {
        if (k + 1 < NK) {
            GLDS_B(k + 1);                 // DMA in flight through COMPUTE(k)
            LOAD_A(k + 1);                 // reg loads in flight through COMPUTE(k)
        }
        COMPUTE(k);
        if (k + 1 < NK) WRITE_A((k + 1) & 1);  // pack: waits loadA(k+1)+gldsB(k+1)
        asm volatile("s_waitcnt lgkmcnt(0)" ::: "memory");   // ds_writes visible
        __builtin_amdgcn_s_barrier();                         // raw: no vmcnt drain
        __builtin_amdgcn_sched_barrier(0);
        // Race audit (2+2 buffers, one barrier/iter): all reads of buf X at
        // COMPUTE(k-1) precede barrier(k-1); writes to X at iter k follow it.
        // B(k) readiness: pack(k-1)'s vmcnt drains glds(k) before barrier(k-1).
    }

#undef LOAD_A
#undef WRITE_A
#undef GLDS_B
#undef COMPUTE

    // -------- cross-K-group reduction via LDS, then store (h=0 only) --------
    __syncthreads();
    if (h == 1) {
#pragma unroll
        for (int m2 = 0; m2 < 2; ++m2)
#pragma unroll
            for (int n2 = 0; n2 < 2; ++n2) {
                unsigned char* base = smem + (wave - 4) * 16384 + (m2 * 2 + n2) * 4096 + lane * 16;
#pragma unroll
                for (int r4 = 0; r4 < 4; ++r4) {
                    f32x4 v = { acc[m2][n2][r4 * 4 + 0], acc[m2][n2][r4 * 4 + 1],
                                acc[m2][n2][r4 * 4 + 2], acc[m2][n2][r4 * 4 + 3] };
                    *(f32x4*)(base + r4 * 1024) = v;
                }
            }
    }
    __syncthreads();
    if (h == 0) {
#pragma unroll
        for (int m2 = 0; m2 < 2; ++m2)
#pragma unroll
            for (int n2 = 0; n2 < 2; ++n2) {
                const unsigned char* base = smem + wave * 16384 + (m2 * 2 + n2) * 4096 + lane * 16;
#pragma unroll
                for (int r4 = 0; r4 < 4; ++r4) {
                    f32x4 v = *(const f32x4*)(base + r4 * 1024);
#pragma unroll
                    for (int j = 0; j < 4; ++j) acc[m2][n2][r4 * 4 + j] += v[j];
                }
            }
        const int s_w = mt * 128 + wm * 64;
        const int c_w = nt * 128 + wn * 64;
        float* outp = out + BC;
#pragma unroll
        for (int m2 = 0; m2 < 2; ++m2)
#pragma unroll
            for (int n2 = 0; n2 < 2; ++n2)
#pragma unroll
                for (int r = 0; r < 16; ++r) {
                    const int row = (r & 3) + 8 * (r >> 2) + 4 * kg;
                    outp[(size_t)(s_w + m2 * 32 + row) * BC + b * C + c_w + n2 * 32 + lm]
                        = acc[m2][n2][r];
                }
    }
}

// out[0,b,c] = leftmost[c]  (standalone, used only by the fallback path)
__global__ void left_fill(const float* __restrict__ left, float* __restrict__ out) {
    int i = blockIdx.x * blockDim.x + threadIdx.x;
    if (i < BC) out[i] = left[i & (C - 1)];
}

// ---------- FALLBACK (ws too small): round-8 champion kernel verbatim ----------
__global__ __launch_bounds__(512, 4) void ds_gemm_fb(
    const float* __restrict__ x, const float* __restrict__ mask, float* __restrict__ out)
{
    __shared__ __align__(16) unsigned char smem[65536];
    const int bid0 = blockIdx.x;
    const int xcd = bid0 & 7, slot = bid0 >> 3;
    const int b = xcd, mt = slot & 15, nt = (slot >> 4) & 3;
    const int tid = threadIdx.x, lane = tid & 63, wave = tid >> 6;
    const int h = wave >> 2, wq = wave & 3, wm = wq >> 1, wn = wq & 1;
    const int lm = lane & 31, kg = lane >> 5;
    const int ii = tid & 255, sg = ii & 31, tg = ii >> 5;
    const bool stB = (tid >= 256);
    const float* gsrc = stB
        ? x    + (size_t)(tg * 8) * BC + b * C + nt * 128 + sg * 4
        : mask + (size_t)b * T * S + (size_t)(tg * 8) * S + mt * 128 + sg * 4;
    const size_t grow = stB ? (size_t)BC : (size_t)S;
    const size_t gstep = grow * BK;
    int waddr[4];
#pragma unroll
    for (int j = 0; j < 4; ++j)
        waddr[j] = (stB ? 16384 : 0) + tg * 2048 + slot16(sg * 4 + j) * 16;
    int raddrA[2][2], raddrB[2][2];
#pragma unroll
    for (int kk = 0; kk < 2; ++kk)
#pragma unroll
        for (int q = 0; q < 2; ++q) {
            const int oct = h * 4 + kk * 2 + kg;
            raddrA[kk][q] = oct * 2048 + slot16(wm * 64 + q * 32 + lm) * 16;
            raddrB[kk][q] = 16384 + oct * 2048 + slot16(wn * 64 + q * 32 + lm) * 16;
        }
    f32x16 acc[2][2] = {};
    f32x4 L[8];
#define LOAD_TILE(k) { const float* p_ = gsrc + (size_t)(k) * gstep; \
    _Pragma("unroll") for (int r = 0; r < 8; ++r) L[r] = *(const f32x4*)(p_ + (size_t)r * grow); }
#define WRITE_TILE(buf) { const int boff_ = (buf) * 32768; \
    _Pragma("unroll") for (int j = 0; j < 4; ++j) { uint4 w_; \
        w_.x = pk2(L[0][j], L[1][j]); w_.y = pk2(L[2][j], L[3][j]); \
        w_.z = pk2(L[4][j], L[5][j]); w_.w = pk2(L[6][j], L[7][j]); \
        *(uint4*)(smem + boff_ + waddr[j]) = w_; } }
#define COMPUTE(buf) { const int boff_ = (buf) * 32768; \
    _Pragma("unroll") for (int kk = 0; kk < 2; ++kk) { \
        bf16x8 a0_ = *(const bf16x8*)(smem + boff_ + raddrA[kk][0]); \
        bf16x8 a1_ = *(const bf16x8*)(smem + boff_ + raddrA[kk][1]); \
        bf16x8 b0_ = *(const bf16x8*)(smem + boff_ + raddrB[kk][0]); \
        bf16x8 b1_ = *(const bf16x8*)(smem + boff_ + raddrB[kk][1]); \
        acc[0][0] = __builtin_amdgcn_mfma_f32_32x32x16_bf16(a0_, b0_, acc[0][0], 0, 0, 0); \
        acc[0][1] = __builtin_amdgcn_mfma_f32_32x32x16_bf16(a0_, b1_, acc[0][1], 0, 0, 0); \
        acc[1][0] = __builtin_amdgcn_mfma_f32_32x32x16_bf16(a1_, b0_, acc[1][0], 0, 0, 0); \
        acc[1][1] = __builtin_amdgcn_mfma_f32_32x32x16_bf16(a1_, b1_, acc[1][1], 0, 0, 0); } }
    LOAD_TILE(0);
    for (int k = 0; k < NK; ++k) {
        WRITE_TILE(k & 1);
        if (k + 1 < NK) LOAD_TILE(k + 1);
        __syncthreads();
        COMPUTE(k & 1);
    }
#undef LOAD_TILE
#undef WRITE_TILE
#undef COMPUTE
    __syncthreads();
    if (h == 1) {
#pragma unroll
        for (int m2 = 0; m2 < 2; ++m2)
#pragma unroll
            for (int n2 = 0; n2 < 2; ++n2) {
                unsigned char* base = smem + (wave - 4) * 16384 + (m2 * 2 + n2) * 4096 + lane * 16;
#pragma unroll
                for (int r4 = 0; r4 < 4; ++r4) {
                    f32x4 v = { acc[m2][n2][r4 * 4 + 0], acc[m2][n2][r4 * 4 + 1],
                                acc[m2][n2][r4 * 4 + 2], acc[m2][n2][r4 * 4 + 3] };
                    *(f32x4*)(base + r4 * 1024) = v;
                }
            }
    }
    __syncthreads();
    if (h == 0) {
#pragma unroll
        for (int m2 = 0; m2 < 2; ++m2)
#pragma unroll
            for (int n2 = 0; n2 < 2; ++n2) {
                const unsigned char* base = smem + wave * 16384 + (m2 * 2 + n2) * 4096 + lane * 16;
#pragma unroll
                for (int r4 = 0; r4 < 4; ++r4) {
                    f32x4 v = *(const f32x4*)(base + r4 * 1024);
#pragma unroll
                    for (int j = 0; j < 4; ++j) acc[m2][n2][r4 * 4 + j] += v[j];
                }
            }
        const int s_w = mt * 128 + wm * 64;
        const int c_w = nt * 128 + wn * 64;
        float* outp = out + BC;
#pragma unroll
    for (int m2 = 0; m2 < 2; ++m2)
#pragma unroll
        for (int n2 = 0; n2 < 2; ++n2)
#pragma unroll
            for (int r = 0; r < 16; ++r) {
                const int row = (r & 3) + 8 * (r >> 2) + 4 * kg;
                outp[(size_t)(s_w + m2 * 32 + row) * BC + b * C + c_w + n2 * 32 + lm]
                    = acc[m2][n2][r];
            }
    }
}

extern "C" void kernel_launch(void* const* d_in, const int* in_sizes, int n_in,
                              void* d_out, int out_size, void* d_ws, size_t ws_size,
                              hipStream_t stream) {
    const float* x    = (const float*)d_in[0];  // [T,B,C] fp32
    const float* mask = (const float*)d_in[1];  // [B,T,S] fp32
    const float* left = (const float*)d_in[3];  // [1,1,C] fp32
    float* out = (float*)d_out;                 // [S+1,B,C] fp32

    const size_t XT_BYTES = (size_t)T * Bb * C * sizeof(__bf16);  // 32 MiB
    if (ws_size >= XT_BYTES) {
        __bf16* xT = (__bf16*)d_ws;
        transpose_x<<<Bb * (T / 64) * (C / 64), 256, 0, stream>>>(x, xT, left, out);
        ds_gemm_glds<<<Bb * (S / 128) * (C / 128), 512, 0, stream>>>(xT, mask, out);
    } else {
        left_fill<<<BC / 256, 256, 0, stream>>>(left, out);
        ds_gemm_fb<<<Bb * (S / 128) * (C / 128), 512, 0, stream>>>(x, mask, out);
    }
}